// Round 4
// baseline (1028.520 us; speedup 1.0000x reference)
//
#include <hip/hip_runtime.h>

typedef __attribute__((ext_vector_type(8))) short short8;
typedef __attribute__((ext_vector_type(4))) float f32x4;

#define T_TOK  131072
#define DMODEL 256
#define DHID   512
#define NEXP   8

// ---------------- ws layout (bytes) ----------------
// xb        : 0          size 67108864   (T*256 bf16)
// w1b       : 67108864   size 2097152
// w2b       : 69206016   size 2097152
// tok_list  : 71303168   size 4194304    (E*T int)
// wt_list   : 75497472   size 4194304    (E*T float)
// pack      : 79691776   size 524288     (T int)
// tkw       : 80216064   size 1048576    (T float2)
// part_cnt  : 81264640   size 65536      (2048*8 int)
// part_psum : 81526784   size 65536
// block_off : 81788928   size 65536
// cnt_total : 82051072   size 32

__device__ __forceinline__ unsigned short f2bf(float f) {
  unsigned int u = __float_as_uint(f);
  u = (u + 0x7FFFu + ((u >> 16) & 1u)) >> 16;
  return (unsigned short)u;
}

__device__ __forceinline__ void gload16(const void* g, void* l) {
  __builtin_amdgcn_global_load_lds(
      (const __attribute__((address_space(1))) void*)g,
      (__attribute__((address_space(3))) void*)l, 16, 0, 0);
}

// ---------------- weight fp32 -> bf16 ----------------
__global__ void k_wconv(const float* __restrict__ w1, const float* __restrict__ w2,
                        unsigned short* __restrict__ w1b, unsigned short* __restrict__ w2b) {
  int i = blockIdx.x * 256 + threadIdx.x;
  float4 a = ((const float4*)w1)[i];
  ushort4 ua; ua.x = f2bf(a.x); ua.y = f2bf(a.y); ua.z = f2bf(a.z); ua.w = f2bf(a.w);
  ((ushort4*)w1b)[i] = ua;
  float4 b = ((const float4*)w2)[i];
  ushort4 ub; ub.x = f2bf(b.x); ub.y = f2bf(b.y); ub.z = f2bf(b.z); ub.w = f2bf(b.w);
  ((ushort4*)w2b)[i] = ub;
}

// ---------------- router: fp64 logits (bit-identical math), 64 tok/block ----------------
__global__ __launch_bounds__(256) void k_router(
    const float* __restrict__ x, const float* __restrict__ gate,
    unsigned short* __restrict__ xb, int* __restrict__ pack, float2* __restrict__ tkw,
    int* __restrict__ part_cnt, float* __restrict__ part_psum) {
  __shared__ float g[NEXP][DMODEL];
  __shared__ int s_cnt[NEXP];
  __shared__ float s_ps[NEXP];
  int tid = threadIdx.x;
  for (int i = tid; i < NEXP * DMODEL; i += 256) g[i >> 8][i & 255] = gate[i];
  if (tid < NEXP) { s_cnt[tid] = 0; s_ps[tid] = 0.f; }
  __syncthreads();
  int lane = tid & 63, wv = tid >> 6;
  float psacc[NEXP] = {0.f,0.f,0.f,0.f,0.f,0.f,0.f,0.f};
  for (int k = 0; k < 16; ++k) {
    int t = (blockIdx.x << 6) + (wv << 4) + k;
    const float* xr = x + (size_t)t * DMODEL;
    float4 x4 = *(const float4*)(xr + 4 * lane);
    ushort4 u4;
    u4.x = f2bf(x4.x); u4.y = f2bf(x4.y); u4.z = f2bf(x4.z); u4.w = f2bf(x4.w);
    *(ushort4*)(xb + (size_t)t * DMODEL + 4 * lane) = u4;
    double l[NEXP];
#pragma unroll
    for (int e = 0; e < NEXP; ++e) {
      const float4 g4 = *(const float4*)&g[e][4 * lane];
      l[e] = (double)x4.x * (double)g4.x + (double)x4.y * (double)g4.y +
             (double)x4.z * (double)g4.z + (double)x4.w * (double)g4.w;
    }
#pragma unroll
    for (int e = 0; e < NEXP; ++e) {
#pragma unroll
      for (int d = 32; d; d >>= 1) l[e] += __shfl_xor(l[e], d);
    }
    int i1 = 0;
#pragma unroll
    for (int e = 1; e < NEXP; ++e) if (l[e] > l[i1]) i1 = e;
    int i2 = (i1 == 0) ? 1 : 0;
#pragma unroll
    for (int e = 0; e < NEXP; ++e) if (e != i1 && l[e] > l[i2]) i2 = e;
    double m = l[0];
#pragma unroll
    for (int e = 1; e < NEXP; ++e) m = (l[e] > m) ? l[e] : m;
    float pe[NEXP]; float s = 0.f;
#pragma unroll
    for (int e = 0; e < NEXP; ++e) { pe[e] = __expf((float)(l[e] - m)); s += pe[e]; }
    float inv = 1.f / s;
    float p1 = pe[i1] * inv, p2 = pe[i2] * inv;
    float wn = 1.f / (p1 + p2);
    if (lane == 0) {
      pack[t] = i1 | (i2 << 8);
      tkw[t] = make_float2(p1 * wn, p2 * wn);
      atomicAdd(&s_cnt[i1], 1); atomicAdd(&s_cnt[i2], 1);
#pragma unroll
      for (int e = 0; e < NEXP; ++e) psacc[e] += pe[e] * inv;
    }
  }
  if (lane == 0) {
#pragma unroll
    for (int e = 0; e < NEXP; ++e) atomicAdd(&s_ps[e], psacc[e]);
  }
  __syncthreads();
  if (tid < NEXP) {
    part_cnt[blockIdx.x * NEXP + tid] = s_cnt[tid];
    part_psum[blockIdx.x * NEXP + tid] = s_ps[tid];
  }
}

// ---------------- scan over 2048 router blocks ----------------
__global__ __launch_bounds__(512) void k_scan(
    const int* __restrict__ part_cnt, const float* __restrict__ part_psum,
    int* __restrict__ block_off, int* __restrict__ cnt_total, float* __restrict__ out) {
  __shared__ float s_ps[NEXP];
  __shared__ int s_ct[NEXP];
  int lane = threadIdx.x & 63, wv = threadIdx.x >> 6;
  int base = lane * 32;
  int lsum = 0; float ps = 0.f;
#pragma unroll 8
  for (int j = 0; j < 32; ++j) {
    lsum += part_cnt[(base + j) * NEXP + wv];
    ps += part_psum[(base + j) * NEXP + wv];
  }
  int incl = lsum;
#pragma unroll
  for (int d = 1; d < 64; d <<= 1) { int t = __shfl_up(incl, d); if (lane >= d) incl += t; }
  int run = incl - lsum;
#pragma unroll 8
  for (int j = 0; j < 32; ++j) {
    int v = part_cnt[(base + j) * NEXP + wv];
    block_off[(base + j) * NEXP + wv] = run;
    run += v;
  }
#pragma unroll
  for (int d = 32; d; d >>= 1) ps += __shfl_xor(ps, d);
  int total = __shfl(incl, 63);
  if (lane == 0) { cnt_total[wv] = total; s_ct[wv] = total; s_ps[wv] = ps; }
  __syncthreads();
  if (threadIdx.x == 0) {
    double aux = 0.0;
    for (int e = 0; e < NEXP; ++e)
      aux += ((double)s_ct[e] / 131072.0) * ((double)s_ps[e] / 131072.0);
    out[33554432] = (float)(8.0 * aux);
  }
}

// ---------------- scatter (matches router's 64-token blocking) ----------------
__global__ void k_scatter(const int* __restrict__ pack, const float2* __restrict__ tkw,
                          const int* __restrict__ block_off, int* __restrict__ tok_list,
                          float* __restrict__ wt_list) {
  __shared__ int s_loc[NEXP];
  int tid = threadIdx.x;
  if (tid < NEXP) s_loc[tid] = 0;
  __syncthreads();
  int t = (blockIdx.x << 6) + tid;
  int p = pack[t];
  float2 wv = tkw[t];
  int e1 = p & 255, e2 = (p >> 8) & 255;
  int o1 = block_off[blockIdx.x * NEXP + e1];
  int p1 = atomicAdd(&s_loc[e1], 1);
  tok_list[e1 * T_TOK + o1 + p1] = t;
  wt_list[e1 * T_TOK + o1 + p1] = wv.x;
  int o2 = block_off[blockIdx.x * NEXP + e2];
  int p2 = atomicAdd(&s_loc[e2], 1);
  tok_list[e2 * T_TOK + o2 + p2] = t;
  wt_list[e2 * T_TOK + o2 + p2] = wv.y;
}

// ---------------- fused expert FFN: 64 tok/block, 8 waves, 2 blocks/CU ----------------
// Waves: (tm token-half, nq col-quarter). X staged to LDS (shared gather) then
// held in regs; X buffer is reused for W2 chunks (time-disjoint union) so LDS =
// 73.5KB -> 2 resident blocks -> 4 waves/SIMD from independent blocks fill the
// vmcnt(0) barrier drains. Bijective XCD swizzle gives per-XCD expert locality
// (weights L2-resident). All tiles XOR-swizzled (slot ^= row&7), linear
// gload_lds dest + inverse-swizzled global source.
__global__ __launch_bounds__(512, 4) void k_ffn(
    const unsigned short* __restrict__ xb, const unsigned short* __restrict__ w1b,
    const unsigned short* __restrict__ w2b, const float* __restrict__ b1,
    const float* __restrict__ b2, const int* __restrict__ tok_list,
    const float* __restrict__ wt_list, const int* __restrict__ cnt_total,
    float* __restrict__ out) {
  __shared__ __align__(16) unsigned short W1s[64 * 256];  // 32KB: 64 hid rows x 32 slots
  __shared__ __align__(16) unsigned short XW2[256 * 64];  // 32KB: X(64x32) then W2(256x8)
  __shared__ __align__(16) unsigned short H[64 * 72];     // 9KB, padded stride 72
  __shared__ int s_tok[64];
  __shared__ float s_w[64];

  // bijective XCD swizzle: grid 4104 = 8*513 exactly
  int bid = (blockIdx.x & 7) * 513 + (blockIdx.x >> 3);
  int e = -1, bi = 0, cum = 0;
#pragma unroll
  for (int ee = 0; ee < NEXP; ++ee) {
    int nb = (cnt_total[ee] + 63) >> 6;
    if (e < 0 && bid < cum + nb) { e = ee; bi = bid - cum; }
    cum += nb;
  }
  if (e < 0) return;
  int cnt = cnt_total[e];
  int nv = cnt - (bi << 6); if (nv > 64) nv = 64;

  int tid = threadIdx.x;
  if (tid < 64) {
    int basei = e * T_TOK + (bi << 6);
    int idx = basei + (tid < nv ? tid : 0);
    s_tok[tid] = tok_list[idx];
    s_w[tid] = (tid < nv) ? wt_list[idx] : 0.f;
  }
  __syncthreads();

  int lane = tid & 63, w = tid >> 6;
  int l15 = lane & 15, lg = lane >> 4;
  int tm = w >> 2, nq = w & 3;

  const unsigned short* w1e = w1b + (size_t)e * DHID * DMODEL;
  const unsigned short* w2e = w2b + (size_t)e * DMODEL * DHID;

  // stage X into XW2 (gathered rows; per-lane swizzled source, linear dest)
#pragma unroll
  for (int i = 0; i < 4; ++i) {
    int t = i * 512 + w * 64 + lane;
    int row = t >> 5, c = t & 31;
    gload16(xb + (size_t)s_tok[row] * DMODEL + (size_t)((c ^ (row & 7)) << 3),
            &XW2[(size_t)(i * 512 + w * 64) * 8]);
  }
  // stage W1 chunk 0
#pragma unroll
  for (int i = 0; i < 4; ++i) {
    int t = i * 512 + w * 64 + lane;
    int row = t >> 5, c = t & 31;
    gload16(w1e + (size_t)row * DMODEL + (size_t)((c ^ (row & 7)) << 3),
            &W1s[(size_t)(i * 512 + w * 64) * 8]);
  }
  __syncthreads();  // vmcnt(0): X + W1(0) landed

  // X fragments -> registers (held across all 8 phases)
  short8 xfrag[2][8];
#pragma unroll
  for (int mt = 0; mt < 2; ++mt) {
    int row = tm * 32 + mt * 16 + l15;
    int r7 = row & 7;
#pragma unroll
    for (int ks = 0; ks < 8; ++ks)
      xfrag[mt][ks] = *(const short8*)&XW2[(size_t)(row * 32 + (((ks << 2) | lg) ^ r7)) << 3];
  }
  __syncthreads();  // all xfrag reads done -> XW2 reusable for W2

  // issue W2 chunk 0 into XW2 (flies over GEMM1 of phase 0)
#pragma unroll
  for (int i = 0; i < 4; ++i) {
    int t = i * 512 + w * 64 + lane;
    int row = t >> 3, c = t & 7;
    gload16(w2e + (size_t)row * DHID + (size_t)((c ^ (row & 7)) << 3),
            &XW2[(size_t)(i * 512 + w * 64) * 8]);
  }

  float b1v[8];
#pragma unroll
  for (int cc = 0; cc < 8; ++cc) b1v[cc] = b1[e * DHID + cc * 64 + nq * 16 + l15];

  f32x4 yacc[2][4];
#pragma unroll
  for (int mt = 0; mt < 2; ++mt)
#pragma unroll
    for (int nt = 0; nt < 4; ++nt) yacc[mt][nt] = (f32x4){0.f, 0.f, 0.f, 0.f};

  int brow = nq * 16 + l15;
  int br7 = brow & 7;

  for (int cc = 0; cc < 8; ++cc) {
    // ---- GEMM1: H_chunk[64 x 64] = X @ W1c^T (W2(cc) staging in flight) ----
    f32x4 hacc[2];
    hacc[0] = (f32x4){0.f, 0.f, 0.f, 0.f};
    hacc[1] = (f32x4){0.f, 0.f, 0.f, 0.f};
#pragma unroll
    for (int ks = 0; ks < 8; ++ks) {
      short8 bf = *(const short8*)&W1s[(size_t)(brow * 32 + (((ks << 2) | lg) ^ br7)) << 3];
      hacc[0] = __builtin_amdgcn_mfma_f32_16x16x32_bf16(xfrag[0][ks], bf, hacc[0], 0, 0, 0);
      hacc[1] = __builtin_amdgcn_mfma_f32_16x16x32_bf16(xfrag[1][ks], bf, hacc[1], 0, 0, 0);
    }
    // bias + silu -> H
#pragma unroll
    for (int mt = 0; mt < 2; ++mt)
#pragma unroll
      for (int r = 0; r < 4; ++r) {
        float z = hacc[mt][r] + b1v[cc];
        float sv = z / (1.f + __expf(-z));
        H[(tm * 32 + mt * 16 + lg * 4 + r) * 72 + nq * 16 + l15] = f2bf(sv);
      }
    __syncthreads();  // B1: drains W2(cc); H visible; W1s reads done

    // issue W1(cc+1) -> flies over GEMM2
    if (cc < 7) {
#pragma unroll
      for (int i = 0; i < 4; ++i) {
        int t = i * 512 + w * 64 + lane;
        int row = t >> 5, c = t & 31;
        gload16(w1e + (size_t)((cc + 1) * 64 + row) * DMODEL + (size_t)((c ^ (row & 7)) << 3),
                &W1s[(size_t)(i * 512 + w * 64) * 8]);
      }
    }

    // ---- GEMM2: yacc += H_chunk @ W2c^T ----
#pragma unroll
    for (int ks = 0; ks < 2; ++ks) {
      short8 a0 = *(const short8*)&H[(tm * 32 + l15) * 72 + ks * 32 + lg * 8];
      short8 a1 = *(const short8*)&H[(tm * 32 + 16 + l15) * 72 + ks * 32 + lg * 8];
#pragma unroll
      for (int nt = 0; nt < 4; ++nt) {
        int dr = nq * 64 + nt * 16 + l15;
        short8 bf = *(const short8*)&XW2[(size_t)(dr * 8 + (((ks << 2) | lg) ^ (dr & 7))) << 3];
        yacc[0][nt] = __builtin_amdgcn_mfma_f32_16x16x32_bf16(a0, bf, yacc[0][nt], 0, 0, 0);
        yacc[1][nt] = __builtin_amdgcn_mfma_f32_16x16x32_bf16(a1, bf, yacc[1][nt], 0, 0, 0);
      }
    }
    __syncthreads();  // B2: drains W1(cc+1); XW2 + H reads done

    // issue W2(cc+1) -> flies over next GEMM1
    if (cc < 7) {
#pragma unroll
      for (int i = 0; i < 4; ++i) {
        int t = i * 512 + w * 64 + lane;
        int row = t >> 3, c = t & 7;
        gload16(w2e + (size_t)row * DHID + (size_t)((cc + 1) * 64) + (size_t)((c ^ (row & 7)) << 3),
                &XW2[(size_t)(i * 512 + w * 64) * 8]);
      }
    }
  }

  // epilogue: out += w * (Y + b2), exactly 2 contributions per token element
#pragma unroll
  for (int nt = 0; nt < 4; ++nt) {
    int d = nq * 64 + nt * 16 + l15;
    float b2v = b2[e * DMODEL + d];
#pragma unroll
    for (int mt = 0; mt < 2; ++mt) {
#pragma unroll
      for (int r = 0; r < 4; ++r) {
        int row = tm * 32 + mt * 16 + lg * 4 + r;
        if (row < nv) {
          float val = s_w[row] * (yacc[mt][nt][r] + b2v);
          atomicAdd(out + (size_t)s_tok[row] * DMODEL + d, val);
        }
      }
    }
  }
}

extern "C" void kernel_launch(void* const* d_in, const int* in_sizes, int n_in,
                              void* d_out, int out_size, void* d_ws, size_t ws_size,
                              hipStream_t stream) {
  const float* x    = (const float*)d_in[0];
  const float* gate = (const float*)d_in[1];
  const float* w1   = (const float*)d_in[2];
  const float* b1   = (const float*)d_in[3];
  const float* w2   = (const float*)d_in[4];
  const float* b2   = (const float*)d_in[5];
  float* out = (float*)d_out;
  char* ws = (char*)d_ws;

  unsigned short* xb  = (unsigned short*)(ws);
  unsigned short* w1b = (unsigned short*)(ws + 67108864);
  unsigned short* w2b = (unsigned short*)(ws + 69206016);
  int*    tok_list  = (int*)(ws + 71303168);
  float*  wt_list   = (float*)(ws + 75497472);
  int*    pack      = (int*)(ws + 79691776);
  float2* tkw       = (float2*)(ws + 80216064);
  int*    part_cnt  = (int*)(ws + 81264640);
  float*  part_psum = (float*)(ws + 81526784);
  int*    block_off = (int*)(ws + 81788928);
  int*    cnt_total = (int*)(ws + 82051072);

  hipMemsetAsync(d_out, 0, (size_t)out_size * 4, stream);
  k_wconv<<<1024, 256, 0, stream>>>(w1, w2, w1b, w2b);
  k_router<<<2048, 256, 0, stream>>>(x, gate, xb, pack, tkw, part_cnt, part_psum);
  k_scan<<<1, 512, 0, stream>>>(part_cnt, part_psum, block_off, cnt_total, out);
  k_scatter<<<2048, 64, 0, stream>>>(pack, tkw, block_off, tok_list, wt_list);
  k_ffn<<<4104, 512, 0, stream>>>(xb, w1b, w2b, b1, b2, tok_list, wt_list, cnt_total, out);
}

// Round 6
// 649.484 us; speedup vs baseline: 1.5836x; 1.5836x over previous
//
#include <hip/hip_runtime.h>

typedef __attribute__((ext_vector_type(8))) short short8;
typedef __attribute__((ext_vector_type(4))) float f32x4;

#define T_TOK  131072
#define DMODEL 256
#define DHID   512
#define NEXP   8

// ---------------- ws layout (bytes) ----------------
// xb        : 0          size 67108864   (T*256 bf16)
// w1b       : 67108864   size 2097152
// w2b       : 69206016   size 2097152
// tok_list  : 71303168   size 4194304    (E*T int)
// wt_list   : 75497472   size 4194304    (E*T float)
// pack      : 79691776   size 524288     (T int)
// tkw       : 80216064   size 1048576    (T float2)
// part_cnt  : 81264640   size 65536      (2048*8 int)
// part_psum : 81526784   size 65536
// block_off : 81788928   size 65536
// cnt_total : 82051072   size 64         (int[16]: counts + bases)
// H         : 83886080   size 268566528  ((2T+128) x 512 bf16)  -> total ~336 MB

__device__ __forceinline__ unsigned short f2bf(float f) {
  unsigned int u = __float_as_uint(f);
  u = (u + 0x7FFFu + ((u >> 16) & 1u)) >> 16;
  return (unsigned short)u;
}

__device__ __forceinline__ void gload16(const void* g, void* l) {
  __builtin_amdgcn_global_load_lds(
      (const __attribute__((address_space(1))) void*)g,
      (__attribute__((address_space(3))) void*)l, 16, 0, 0);
}

// ---------------- weight fp32 -> bf16 ----------------
__global__ void k_wconv(const float* __restrict__ w1, const float* __restrict__ w2,
                        unsigned short* __restrict__ w1b, unsigned short* __restrict__ w2b) {
  int i = blockIdx.x * 256 + threadIdx.x;
  float4 a = ((const float4*)w1)[i];
  ushort4 ua; ua.x = f2bf(a.x); ua.y = f2bf(a.y); ua.z = f2bf(a.z); ua.w = f2bf(a.w);
  ((ushort4*)w1b)[i] = ua;
  float4 b = ((const float4*)w2)[i];
  ushort4 ub; ub.x = f2bf(b.x); ub.y = f2bf(b.y); ub.z = f2bf(b.z); ub.w = f2bf(b.w);
  ((ushort4*)w2b)[i] = ub;
}

// ---------------- router: fp64 logits (bit-identical math), 64 tok/block ----------------
__global__ __launch_bounds__(256) void k_router(
    const float* __restrict__ x, const float* __restrict__ gate,
    unsigned short* __restrict__ xb, int* __restrict__ pack, float2* __restrict__ tkw,
    int* __restrict__ part_cnt, float* __restrict__ part_psum) {
  __shared__ float g[NEXP][DMODEL];
  __shared__ int s_cnt[NEXP];
  __shared__ float s_ps[NEXP];
  int tid = threadIdx.x;
  for (int i = tid; i < NEXP * DMODEL; i += 256) g[i >> 8][i & 255] = gate[i];
  if (tid < NEXP) { s_cnt[tid] = 0; s_ps[tid] = 0.f; }
  __syncthreads();
  int lane = tid & 63, wv = tid >> 6;
  float psacc[NEXP] = {0.f,0.f,0.f,0.f,0.f,0.f,0.f,0.f};
  for (int k = 0; k < 16; ++k) {
    int t = (blockIdx.x << 6) + (wv << 4) + k;
    const float* xr = x + (size_t)t * DMODEL;
    float4 x4 = *(const float4*)(xr + 4 * lane);
    ushort4 u4;
    u4.x = f2bf(x4.x); u4.y = f2bf(x4.y); u4.z = f2bf(x4.z); u4.w = f2bf(x4.w);
    *(ushort4*)(xb + (size_t)t * DMODEL + 4 * lane) = u4;
    double l[NEXP];
#pragma unroll
    for (int e = 0; e < NEXP; ++e) {
      const float4 g4 = *(const float4*)&g[e][4 * lane];
      l[e] = (double)x4.x * (double)g4.x + (double)x4.y * (double)g4.y +
             (double)x4.z * (double)g4.z + (double)x4.w * (double)g4.w;
    }
#pragma unroll
    for (int e = 0; e < NEXP; ++e) {
#pragma unroll
      for (int d = 32; d; d >>= 1) l[e] += __shfl_xor(l[e], d);
    }
    int i1 = 0;
#pragma unroll
    for (int e = 1; e < NEXP; ++e) if (l[e] > l[i1]) i1 = e;
    int i2 = (i1 == 0) ? 1 : 0;
#pragma unroll
    for (int e = 0; e < NEXP; ++e) if (e != i1 && l[e] > l[i2]) i2 = e;
    double m = l[0];
#pragma unroll
    for (int e = 1; e < NEXP; ++e) m = (l[e] > m) ? l[e] : m;
    float pe[NEXP]; float s = 0.f;
#pragma unroll
    for (int e = 0; e < NEXP; ++e) { pe[e] = __expf((float)(l[e] - m)); s += pe[e]; }
    float inv = 1.f / s;
    float p1 = pe[i1] * inv, p2 = pe[i2] * inv;
    float wn = 1.f / (p1 + p2);
    if (lane == 0) {
      pack[t] = i1 | (i2 << 8);
      tkw[t] = make_float2(p1 * wn, p2 * wn);
      atomicAdd(&s_cnt[i1], 1); atomicAdd(&s_cnt[i2], 1);
#pragma unroll
      for (int e = 0; e < NEXP; ++e) psacc[e] += pe[e] * inv;
    }
  }
  if (lane == 0) {
#pragma unroll
    for (int e = 0; e < NEXP; ++e) atomicAdd(&s_ps[e], psacc[e]);
  }
  __syncthreads();
  if (tid < NEXP) {
    part_cnt[blockIdx.x * NEXP + tid] = s_cnt[tid];
    part_psum[blockIdx.x * NEXP + tid] = s_ps[tid];
  }
}

// ---------------- scan: offsets, totals, expert bases, aux loss ----------------
__global__ __launch_bounds__(512) void k_scan(
    const int* __restrict__ part_cnt, const float* __restrict__ part_psum,
    int* __restrict__ block_off, int* __restrict__ cnt_total, float* __restrict__ out) {
  __shared__ float s_ps[NEXP];
  __shared__ int s_ct[NEXP];
  int lane = threadIdx.x & 63, wv = threadIdx.x >> 6;
  int base = lane * 32;
  int lsum = 0; float ps = 0.f;
#pragma unroll 8
  for (int j = 0; j < 32; ++j) {
    lsum += part_cnt[(base + j) * NEXP + wv];
    ps += part_psum[(base + j) * NEXP + wv];
  }
  int incl = lsum;
#pragma unroll
  for (int d = 1; d < 64; d <<= 1) { int t = __shfl_up(incl, d); if (lane >= d) incl += t; }
  int run = incl - lsum;
#pragma unroll 8
  for (int j = 0; j < 32; ++j) {
    int v = part_cnt[(base + j) * NEXP + wv];
    block_off[(base + j) * NEXP + wv] = run;
    run += v;
  }
#pragma unroll
  for (int d = 32; d; d >>= 1) ps += __shfl_xor(ps, d);
  int total = __shfl(incl, 63);
  if (lane == 0) { cnt_total[wv] = total; s_ct[wv] = total; s_ps[wv] = ps; }
  __syncthreads();
  if (threadIdx.x == 0) {
    double aux = 0.0; int rb = 0;
    for (int e = 0; e < NEXP; ++e) {
      aux += ((double)s_ct[e] / 131072.0) * ((double)s_ps[e] / 131072.0);
      cnt_total[8 + e] = rb; rb += s_ct[e];
    }
    out[33554432] = (float)(8.0 * aux);
  }
}

// ---------------- scatter (matches router's 64-token blocking) ----------------
__global__ void k_scatter(const int* __restrict__ pack, const float2* __restrict__ tkw,
                          const int* __restrict__ block_off, int* __restrict__ tok_list,
                          float* __restrict__ wt_list) {
  __shared__ int s_loc[NEXP];
  int tid = threadIdx.x;
  if (tid < NEXP) s_loc[tid] = 0;
  __syncthreads();
  int t = (blockIdx.x << 6) + tid;
  int p = pack[t];
  float2 wv = tkw[t];
  int e1 = p & 255, e2 = (p >> 8) & 255;
  int o1 = block_off[blockIdx.x * NEXP + e1];
  int p1 = atomicAdd(&s_loc[e1], 1);
  tok_list[e1 * T_TOK + o1 + p1] = t;
  wt_list[e1 * T_TOK + o1 + p1] = wv.x;
  int o2 = block_off[blockIdx.x * NEXP + e2];
  int p2 = atomicAdd(&s_loc[e2], 1);
  tok_list[e2 * T_TOK + o2 + p2] = t;
  wt_list[e2 * T_TOK + o2 + p2] = wv.y;
}

// ---------------- grouped GEMM1 + silu: H[slot,512] = silu(X @ W1^T + b1) ----------------
// 128x128 tile, K=256, BK=32, dbuf LDS 32KB, 256 thr / 4 waves, 3 blocks/CU.
// H store guarded row<nv: expert H bases are dense, so padded rows of a last
// tile would alias the NEXT expert's rows (the round-5 race). Never write them.
__global__ __launch_bounds__(256, 3) void k_gemm1(
    const unsigned short* __restrict__ xb, const unsigned short* __restrict__ w1b,
    const float* __restrict__ b1, const int* __restrict__ tok_list,
    const int* __restrict__ cnt_total, unsigned short* __restrict__ H) {
  __shared__ __align__(16) unsigned short buf[16384];  // A0 A1 B0 B1 (4KB-u16 each)
  __shared__ int s_tok[128];

  int bid = blockIdx.x;
  int e = -1, loc = 0, cum = 0, cnte = 0;
#pragma unroll
  for (int ee = 0; ee < NEXP; ++ee) {
    int ct = cnt_total[ee];
    int nb = ((ct + 127) >> 7) * 4;
    if (e < 0 && bid < cum + nb) { e = ee; loc = bid - cum; cnte = ct; }
    cum += nb;
  }
  if (e < 0) return;
  int mi = loc >> 2, ni = loc & 3;
  int nv = cnte - (mi << 7); if (nv > 128) nv = 128;

  int tid = threadIdx.x;
  if (tid < 128) s_tok[tid] = tok_list[e * T_TOK + (mi << 7) + (tid < nv ? tid : nv - 1)];
  __syncthreads();

  int lane = tid & 63, w = tid >> 6, l15 = lane & 15, lg = lane >> 4;
  int m0 = (w >> 1) * 64, n0 = (w & 1) * 64;
  const unsigned short* w1e = w1b + ((size_t)e * DHID + ni * 128) * DMODEL;

  auto stage = [&](int cc, int bufi) {
#pragma unroll
    for (int i = 0; i < 2; ++i) {
      int t = i * 256 + tid;
      int row = t >> 2, c = t & 3;
      gload16(xb + (size_t)s_tok[row] * DMODEL + cc * 32 + ((c ^ (row & 3)) << 3),
              &buf[bufi * 4096 + (i * 256 + w * 64) * 8]);
    }
#pragma unroll
    for (int i = 0; i < 2; ++i) {
      int t = i * 256 + tid;
      int row = t >> 2, c = t & 3;
      gload16(w1e + (size_t)row * DMODEL + cc * 32 + ((c ^ (row & 3)) << 3),
              &buf[8192 + bufi * 4096 + (i * 256 + w * 64) * 8]);
    }
  };

  f32x4 acc[4][4];
#pragma unroll
  for (int mt = 0; mt < 4; ++mt)
#pragma unroll
    for (int nt = 0; nt < 4; ++nt) acc[mt][nt] = (f32x4){0.f, 0.f, 0.f, 0.f};

  stage(0, 0);
  __syncthreads();

  for (int cc = 0; cc < 8; ++cc) {
    if (cc < 7) stage(cc + 1, (cc + 1) & 1);
    int bb = (cc & 1) * 4096;
    short8 a[4], b[4];
#pragma unroll
    for (int mt = 0; mt < 4; ++mt) {
      int r = m0 + mt * 16 + l15;
      a[mt] = *(const short8*)&buf[bb + r * 32 + ((lg ^ (r & 3)) << 3)];
    }
#pragma unroll
    for (int nt = 0; nt < 4; ++nt) {
      int r = n0 + nt * 16 + l15;
      b[nt] = *(const short8*)&buf[8192 + bb + r * 32 + ((lg ^ (r & 3)) << 3)];
    }
#pragma unroll
    for (int mt = 0; mt < 4; ++mt)
#pragma unroll
      for (int nt = 0; nt < 4; ++nt)
        acc[mt][nt] = __builtin_amdgcn_mfma_f32_16x16x32_bf16(a[mt], b[nt], acc[mt][nt], 0, 0, 0);
    __syncthreads();
  }

  // epilogue: bias+silu -> LDS (XOR by (row>>2)&3) -> vectorized H store (row<nv only!)
  float b1v[4];
#pragma unroll
  for (int nt = 0; nt < 4; ++nt) b1v[nt] = b1[e * DHID + ni * 128 + n0 + nt * 16 + l15];
#pragma unroll
  for (int mt = 0; mt < 4; ++mt)
#pragma unroll
    for (int nt = 0; nt < 4; ++nt)
#pragma unroll
      for (int rr = 0; rr < 4; ++rr) {
        int row = m0 + mt * 16 + lg * 4 + rr;
        int col = n0 + nt * 16 + l15;
        float z = acc[mt][nt][rr] + b1v[nt];
        float sv = z / (1.f + __expf(-z));
        buf[row * 128 + (col ^ (((row >> 2) & 3) << 3))] = f2bf(sv);
      }
  __syncthreads();
  int hb = cnt_total[8 + e];
#pragma unroll
  for (int i = 0; i < 8; ++i) {
    int t = i * 256 + tid;
    int row = t >> 4, c = t & 15;
    if (row < nv) {
      short8 v = *(const short8*)&buf[row * 128 + ((c ^ ((row >> 2) & 3)) << 3)];
      *(short8*)&H[(size_t)(hb + (mi << 7) + row) * DHID + ni * 128 + (c << 3)] = v;
    }
  }
}

// ---------------- grouped GEMM2 + scale + scatter: out += w*(H @ W2^T + b2) ----------------
// 128x128 tile, K=512, BK=32 (16 steps). A = H (contiguous, no gather). Reads of
// padded A rows may touch the next expert's valid H rows (harmless; epilogue
// guards row<nv); final expert's overrun stays inside H's +128-row slack.
__global__ __launch_bounds__(256, 3) void k_gemm2(
    const unsigned short* __restrict__ H, const unsigned short* __restrict__ w2b,
    const float* __restrict__ b2, const int* __restrict__ tok_list,
    const float* __restrict__ wt_list, const int* __restrict__ cnt_total,
    float* __restrict__ out) {
  __shared__ __align__(16) unsigned short buf[16384];
  __shared__ int s_tok[128];
  __shared__ float s_wt[128];

  int bid = blockIdx.x;
  int e = -1, loc = 0, cum = 0, cnte = 0;
#pragma unroll
  for (int ee = 0; ee < NEXP; ++ee) {
    int ct = cnt_total[ee];
    int nb = ((ct + 127) >> 7) * 2;
    if (e < 0 && bid < cum + nb) { e = ee; loc = bid - cum; cnte = ct; }
    cum += nb;
  }
  if (e < 0) return;
  int mi = loc >> 1, ni = loc & 1;
  int nv = cnte - (mi << 7); if (nv > 128) nv = 128;

  int tid = threadIdx.x;
  if (tid < 128) {
    int idx = e * T_TOK + (mi << 7) + (tid < nv ? tid : nv - 1);
    s_tok[tid] = tok_list[idx];
    s_wt[tid] = (tid < nv) ? wt_list[idx] : 0.f;
  }
  __syncthreads();

  int lane = tid & 63, w = tid >> 6, l15 = lane & 15, lg = lane >> 4;
  int m0 = (w >> 1) * 64, n0 = (w & 1) * 64;
  int hb = cnt_total[8 + e];
  const unsigned short* hrows = H + (size_t)(hb + (mi << 7)) * DHID;
  const unsigned short* w2e = w2b + ((size_t)e * DMODEL + ni * 128) * DHID;

  auto stage = [&](int cc, int bufi) {
#pragma unroll
    for (int i = 0; i < 2; ++i) {
      int t = i * 256 + tid;
      int row = t >> 2, c = t & 3;
      gload16(hrows + (size_t)row * DHID + cc * 32 + ((c ^ (row & 3)) << 3),
              &buf[bufi * 4096 + (i * 256 + w * 64) * 8]);
    }
#pragma unroll
    for (int i = 0; i < 2; ++i) {
      int t = i * 256 + tid;
      int row = t >> 2, c = t & 3;
      gload16(w2e + (size_t)row * DHID + cc * 32 + ((c ^ (row & 3)) << 3),
              &buf[8192 + bufi * 4096 + (i * 256 + w * 64) * 8]);
    }
  };

  f32x4 acc[4][4];
#pragma unroll
  for (int mt = 0; mt < 4; ++mt)
#pragma unroll
    for (int nt = 0; nt < 4; ++nt) acc[mt][nt] = (f32x4){0.f, 0.f, 0.f, 0.f};

  stage(0, 0);
  __syncthreads();

  for (int cc = 0; cc < 16; ++cc) {
    if (cc < 15) stage(cc + 1, (cc + 1) & 1);
    int bb = (cc & 1) * 4096;
    short8 a[4], b[4];
#pragma unroll
    for (int mt = 0; mt < 4; ++mt) {
      int r = m0 + mt * 16 + l15;
      a[mt] = *(const short8*)&buf[bb + r * 32 + ((lg ^ (r & 3)) << 3)];
    }
#pragma unroll
    for (int nt = 0; nt < 4; ++nt) {
      int r = n0 + nt * 16 + l15;
      b[nt] = *(const short8*)&buf[8192 + bb + r * 32 + ((lg ^ (r & 3)) << 3)];
    }
#pragma unroll
    for (int mt = 0; mt < 4; ++mt)
#pragma unroll
      for (int nt = 0; nt < 4; ++nt)
        acc[mt][nt] = __builtin_amdgcn_mfma_f32_16x16x32_bf16(a[mt], b[nt], acc[mt][nt], 0, 0, 0);
    __syncthreads();
  }

  // epilogue: out[tok, col] += wt * (acc + b2[col])
  float b2v[4];
#pragma unroll
  for (int nt = 0; nt < 4; ++nt) b2v[nt] = b2[e * DMODEL + ni * 128 + n0 + nt * 16 + l15];
#pragma unroll
  for (int mt = 0; mt < 4; ++mt)
#pragma unroll
    for (int rr = 0; rr < 4; ++rr) {
      int row = m0 + mt * 16 + lg * 4 + rr;
      if (row < nv) {
        float wt = s_wt[row];
        float* orow = out + (size_t)s_tok[row] * DMODEL + ni * 128;
#pragma unroll
        for (int nt = 0; nt < 4; ++nt)
          atomicAdd(orow + n0 + nt * 16 + l15, wt * (acc[mt][nt][rr] + b2v[nt]));
      }
    }
}

extern "C" void kernel_launch(void* const* d_in, const int* in_sizes, int n_in,
                              void* d_out, int out_size, void* d_ws, size_t ws_size,
                              hipStream_t stream) {
  const float* x    = (const float*)d_in[0];
  const float* gate = (const float*)d_in[1];
  const float* w1   = (const float*)d_in[2];
  const float* b1   = (const float*)d_in[3];
  const float* w2   = (const float*)d_in[4];
  const float* b2   = (const float*)d_in[5];
  float* out = (float*)d_out;
  char* ws = (char*)d_ws;

  unsigned short* xb  = (unsigned short*)(ws);
  unsigned short* w1b = (unsigned short*)(ws + 67108864);
  unsigned short* w2b = (unsigned short*)(ws + 69206016);
  int*    tok_list  = (int*)(ws + 71303168);
  float*  wt_list   = (float*)(ws + 75497472);
  int*    pack      = (int*)(ws + 79691776);
  float2* tkw       = (float2*)(ws + 80216064);
  int*    part_cnt  = (int*)(ws + 81264640);
  float*  part_psum = (float*)(ws + 81526784);
  int*    block_off = (int*)(ws + 81788928);
  int*    cnt_total = (int*)(ws + 82051072);
  unsigned short* H = (unsigned short*)(ws + 83886080);

  hipMemsetAsync(d_out, 0, (size_t)out_size * 4, stream);
  k_wconv<<<1024, 256, 0, stream>>>(w1, w2, w1b, w2b);
  k_router<<<2048, 256, 0, stream>>>(x, gate, xb, pack, tkw, part_cnt, part_psum);
  k_scan<<<1, 512, 0, stream>>>(part_cnt, part_psum, block_off, cnt_total, out);
  k_scatter<<<2048, 64, 0, stream>>>(pack, tkw, block_off, tok_list, wt_list);
  k_gemm1<<<8224, 256, 0, stream>>>(xb, w1b, b1, tok_list, cnt_total, H);
  k_gemm2<<<4112, 256, 0, stream>>>(H, w2b, b2, tok_list, wt_list, cnt_total, out);
}

// Round 7
// 633.282 us; speedup vs baseline: 1.6241x; 1.0256x over previous
//
#include <hip/hip_runtime.h>

typedef __attribute__((ext_vector_type(8))) short short8;
typedef __attribute__((ext_vector_type(4))) float f32x4;

#define T_TOK  131072
#define DMODEL 256
#define DHID   512
#define NEXP   8

// ---------------- ws layout (bytes) ----------------
// xb        : 0          size 67108864   (T*256 bf16)
// w1b       : 67108864   size 2097152
// w2b       : 69206016   size 2097152
// tok_list  : 71303168   size 4194304    (E*T int)
// wt_list   : 75497472   size 4194304    (E*T float)
// pack      : 79691776   size 524288     (T int)
// tkw       : 80216064   size 1048576    (T float2)
// part_cnt  : 81264640   size 65536      (2048*8 int)
// part_psum : 81526784   size 65536
// block_off : 81788928   size 65536
// cnt_total : 82051072   size 64         (int[16]: counts + bases)
// H         : 83886080   size 268566528  ((2T+128) x 512 bf16)  -> total ~336 MB

__device__ __forceinline__ unsigned short f2bf(float f) {
  unsigned int u = __float_as_uint(f);
  u = (u + 0x7FFFu + ((u >> 16) & 1u)) >> 16;
  return (unsigned short)u;
}

__device__ __forceinline__ void gload16(const void* g, void* l) {
  __builtin_amdgcn_global_load_lds(
      (const __attribute__((address_space(1))) void*)g,
      (__attribute__((address_space(3))) void*)l, 16, 0, 0);
}

// ---------------- weight fp32 -> bf16 ----------------
__global__ void k_wconv(const float* __restrict__ w1, const float* __restrict__ w2,
                        unsigned short* __restrict__ w1b, unsigned short* __restrict__ w2b) {
  int i = blockIdx.x * 256 + threadIdx.x;
  float4 a = ((const float4*)w1)[i];
  ushort4 ua; ua.x = f2bf(a.x); ua.y = f2bf(a.y); ua.z = f2bf(a.z); ua.w = f2bf(a.w);
  ((ushort4*)w1b)[i] = ua;
  float4 b = ((const float4*)w2)[i];
  ushort4 ub; ub.x = f2bf(b.x); ub.y = f2bf(b.y); ub.z = f2bf(b.z); ub.w = f2bf(b.w);
  ((ushort4*)w2b)[i] = ub;
}

// ---------------- router: fp64 logits (bit-identical math), 64 tok/block ----------------
__global__ __launch_bounds__(256) void k_router(
    const float* __restrict__ x, const float* __restrict__ gate,
    unsigned short* __restrict__ xb, int* __restrict__ pack, float2* __restrict__ tkw,
    int* __restrict__ part_cnt, float* __restrict__ part_psum) {
  __shared__ float g[NEXP][DMODEL];
  __shared__ int s_cnt[NEXP];
  __shared__ float s_ps[NEXP];
  int tid = threadIdx.x;
  for (int i = tid; i < NEXP * DMODEL; i += 256) g[i >> 8][i & 255] = gate[i];
  if (tid < NEXP) { s_cnt[tid] = 0; s_ps[tid] = 0.f; }
  __syncthreads();
  int lane = tid & 63, wv = tid >> 6;
  float psacc[NEXP] = {0.f,0.f,0.f,0.f,0.f,0.f,0.f,0.f};
  for (int k = 0; k < 16; ++k) {
    int t = (blockIdx.x << 6) + (wv << 4) + k;
    const float* xr = x + (size_t)t * DMODEL;
    float4 x4 = *(const float4*)(xr + 4 * lane);
    ushort4 u4;
    u4.x = f2bf(x4.x); u4.y = f2bf(x4.y); u4.z = f2bf(x4.z); u4.w = f2bf(x4.w);
    *(ushort4*)(xb + (size_t)t * DMODEL + 4 * lane) = u4;
    double l[NEXP];
#pragma unroll
    for (int e = 0; e < NEXP; ++e) {
      const float4 g4 = *(const float4*)&g[e][4 * lane];
      l[e] = (double)x4.x * (double)g4.x + (double)x4.y * (double)g4.y +
             (double)x4.z * (double)g4.z + (double)x4.w * (double)g4.w;
    }
#pragma unroll
    for (int e = 0; e < NEXP; ++e) {
#pragma unroll
      for (int d = 32; d; d >>= 1) l[e] += __shfl_xor(l[e], d);
    }
    int i1 = 0;
#pragma unroll
    for (int e = 1; e < NEXP; ++e) if (l[e] > l[i1]) i1 = e;
    int i2 = (i1 == 0) ? 1 : 0;
#pragma unroll
    for (int e = 0; e < NEXP; ++e) if (e != i1 && l[e] > l[i2]) i2 = e;
    double m = l[0];
#pragma unroll
    for (int e = 1; e < NEXP; ++e) m = (l[e] > m) ? l[e] : m;
    float pe[NEXP]; float s = 0.f;
#pragma unroll
    for (int e = 0; e < NEXP; ++e) { pe[e] = __expf((float)(l[e] - m)); s += pe[e]; }
    float inv = 1.f / s;
    float p1 = pe[i1] * inv, p2 = pe[i2] * inv;
    float wn = 1.f / (p1 + p2);
    if (lane == 0) {
      pack[t] = i1 | (i2 << 8);
      tkw[t] = make_float2(p1 * wn, p2 * wn);
      atomicAdd(&s_cnt[i1], 1); atomicAdd(&s_cnt[i2], 1);
#pragma unroll
      for (int e = 0; e < NEXP; ++e) psacc[e] += pe[e] * inv;
    }
  }
  if (lane == 0) {
#pragma unroll
    for (int e = 0; e < NEXP; ++e) atomicAdd(&s_ps[e], psacc[e]);
  }
  __syncthreads();
  if (tid < NEXP) {
    part_cnt[blockIdx.x * NEXP + tid] = s_cnt[tid];
    part_psum[blockIdx.x * NEXP + tid] = s_ps[tid];
  }
}

// ---------------- scan: offsets, totals, expert bases, aux loss ----------------
__global__ __launch_bounds__(512) void k_scan(
    const int* __restrict__ part_cnt, const float* __restrict__ part_psum,
    int* __restrict__ block_off, int* __restrict__ cnt_total, float* __restrict__ out) {
  __shared__ float s_ps[NEXP];
  __shared__ int s_ct[NEXP];
  int lane = threadIdx.x & 63, wv = threadIdx.x >> 6;
  int base = lane * 32;
  int lsum = 0; float ps = 0.f;
#pragma unroll 8
  for (int j = 0; j < 32; ++j) {
    lsum += part_cnt[(base + j) * NEXP + wv];
    ps += part_psum[(base + j) * NEXP + wv];
  }
  int incl = lsum;
#pragma unroll
  for (int d = 1; d < 64; d <<= 1) { int t = __shfl_up(incl, d); if (lane >= d) incl += t; }
  int run = incl - lsum;
#pragma unroll 8
  for (int j = 0; j < 32; ++j) {
    int v = part_cnt[(base + j) * NEXP + wv];
    block_off[(base + j) * NEXP + wv] = run;
    run += v;
  }
#pragma unroll
  for (int d = 32; d; d >>= 1) ps += __shfl_xor(ps, d);
  int total = __shfl(incl, 63);
  if (lane == 0) { cnt_total[wv] = total; s_ct[wv] = total; s_ps[wv] = ps; }
  __syncthreads();
  if (threadIdx.x == 0) {
    double aux = 0.0; int rb = 0;
    for (int e = 0; e < NEXP; ++e) {
      aux += ((double)s_ct[e] / 131072.0) * ((double)s_ps[e] / 131072.0);
      cnt_total[8 + e] = rb; rb += s_ct[e];
    }
    out[33554432] = (float)(8.0 * aux);
  }
}

// ---------------- scatter (matches router's 64-token blocking) ----------------
__global__ void k_scatter(const int* __restrict__ pack, const float2* __restrict__ tkw,
                          const int* __restrict__ block_off, int* __restrict__ tok_list,
                          float* __restrict__ wt_list) {
  __shared__ int s_loc[NEXP];
  int tid = threadIdx.x;
  if (tid < NEXP) s_loc[tid] = 0;
  __syncthreads();
  int t = (blockIdx.x << 6) + tid;
  int p = pack[t];
  float2 wv = tkw[t];
  int e1 = p & 255, e2 = (p >> 8) & 255;
  int o1 = block_off[blockIdx.x * NEXP + e1];
  int p1 = atomicAdd(&s_loc[e1], 1);
  tok_list[e1 * T_TOK + o1 + p1] = t;
  wt_list[e1 * T_TOK + o1 + p1] = wv.x;
  int o2 = block_off[blockIdx.x * NEXP + e2];
  int p2 = atomicAdd(&s_loc[e2], 1);
  tok_list[e2 * T_TOK + o2 + p2] = t;
  wt_list[e2 * T_TOK + o2 + p2] = wv.y;
}

// ---------------- grouped GEMM1 + silu: H[slot,512] = silu(X @ W1^T + b1) ----------------
// 128x128 tile, K=256, BK=32, tri-buffered A+B (48KB), depth-2 prefetch with
// counted vmcnt(4) + raw s_barrier (T4). Read swizzle slot=c^((r>>1)&3): 16
// lanes -> 8 bank-quads = 2-way (free). XCD-swizzled grid (8224 = 8*1028).
__global__ __launch_bounds__(256, 3) void k_gemm1(
    const unsigned short* __restrict__ xb, const unsigned short* __restrict__ w1b,
    const float* __restrict__ b1, const int* __restrict__ tok_list,
    const int* __restrict__ cnt_total, unsigned short* __restrict__ H) {
  __shared__ __align__(16) unsigned short buf[24576];  // A: 3x4096 u16, B: 3x4096 u16
  __shared__ int s_tok[128];

  int bid = (blockIdx.x & 7) * 1028 + (blockIdx.x >> 3);
  int e = -1, loc = 0, cum = 0, cnte = 0;
#pragma unroll
  for (int ee = 0; ee < NEXP; ++ee) {
    int ct = cnt_total[ee];
    int nb = ((ct + 127) >> 7) * 4;
    if (e < 0 && bid < cum + nb) { e = ee; loc = bid - cum; cnte = ct; }
    cum += nb;
  }
  if (e < 0) return;
  int mi = loc >> 2, ni = loc & 3;
  int nv = cnte - (mi << 7); if (nv > 128) nv = 128;

  int tid = threadIdx.x;
  int lane = tid & 63, w = tid >> 6, l15 = lane & 15, lg = lane >> 4;
  int m0 = (w >> 1) * 64, n0 = (w & 1) * 64;

  // b1 loads issued BEFORE __syncthreads -> drained, not in the counted FIFO
  float b1v[4];
#pragma unroll
  for (int nt = 0; nt < 4; ++nt) b1v[nt] = b1[e * DHID + ni * 128 + n0 + nt * 16 + l15];

  if (tid < 128) s_tok[tid] = tok_list[e * T_TOK + (mi << 7) + (tid < nv ? tid : nv - 1)];
  __syncthreads();

  const unsigned short* w1e = w1b + ((size_t)e * DHID + ni * 128) * DMODEL;

  auto stageA = [&](int cc) {
    int bb = (cc % 3) * 4096;
#pragma unroll
    for (int i = 0; i < 2; ++i) {
      int t = i * 256 + tid;
      int row = t >> 2, c = t & 3;
      gload16(xb + (size_t)s_tok[row] * DMODEL + cc * 32 + ((c ^ ((row >> 1) & 3)) << 3),
              &buf[bb + (i * 256 + w * 64) * 8]);
    }
  };
  auto stageB = [&](int cc) {
    int bb = 12288 + (cc % 3) * 4096;
#pragma unroll
    for (int i = 0; i < 2; ++i) {
      int t = i * 256 + tid;
      int row = t >> 2, c = t & 3;
      gload16(w1e + (size_t)row * DMODEL + cc * 32 + ((c ^ ((row >> 1) & 3)) << 3),
              &buf[bb + (i * 256 + w * 64) * 8]);
    }
  };

  f32x4 acc[4][4];
#pragma unroll
  for (int mt = 0; mt < 4; ++mt)
#pragma unroll
    for (int nt = 0; nt < 4; ++nt) acc[mt][nt] = (f32x4){0.f, 0.f, 0.f, 0.f};

  // prologue: FIFO = [B0,A0, B1,A1]; vmcnt(4) drains B0,A0; B1,A1 stay in flight
  stageB(0); stageA(0); stageB(1); stageA(1);
  asm volatile("s_waitcnt vmcnt(4)" ::: "memory");
  __builtin_amdgcn_s_barrier();
  __builtin_amdgcn_sched_barrier(0);

#pragma unroll
  for (int cc = 0; cc < 8; ++cc) {
    if (cc < 6) { stageB(cc + 2); stageA(cc + 2); }
    int ab = (cc % 3) * 4096, bb = 12288 + (cc % 3) * 4096;
    short8 a[4], b[4];
#pragma unroll
    for (int mt = 0; mt < 4; ++mt) {
      int r = m0 + mt * 16 + l15;
      a[mt] = *(const short8*)&buf[ab + r * 32 + ((lg ^ ((r >> 1) & 3)) << 3)];
    }
#pragma unroll
    for (int nt = 0; nt < 4; ++nt) {
      int r = n0 + nt * 16 + l15;
      b[nt] = *(const short8*)&buf[bb + r * 32 + ((lg ^ ((r >> 1) & 3)) << 3)];
    }
#pragma unroll
    for (int mt = 0; mt < 4; ++mt)
#pragma unroll
      for (int nt = 0; nt < 4; ++nt)
        acc[mt][nt] = __builtin_amdgcn_mfma_f32_16x16x32_bf16(a[mt], b[nt], acc[mt][nt], 0, 0, 0);
    // drain (cc+1)'s staging; leave (cc+2)'s 4 ops in flight
    if (cc < 6) { asm volatile("s_waitcnt vmcnt(4)" ::: "memory"); }
    else        { asm volatile("s_waitcnt vmcnt(0)" ::: "memory"); }
    __builtin_amdgcn_s_barrier();
    __builtin_amdgcn_sched_barrier(0);
  }

  // epilogue: bias+silu -> LDS (XOR by (row>>2)&3) -> vectorized H store (row<nv only!)
#pragma unroll
  for (int mt = 0; mt < 4; ++mt)
#pragma unroll
    for (int nt = 0; nt < 4; ++nt)
#pragma unroll
      for (int rr = 0; rr < 4; ++rr) {
        int row = m0 + mt * 16 + lg * 4 + rr;
        int col = n0 + nt * 16 + l15;
        float z = acc[mt][nt][rr] + b1v[nt];
        float sv = z / (1.f + __expf(-z));
        buf[row * 128 + (col ^ (((row >> 2) & 3) << 3))] = f2bf(sv);
      }
  __syncthreads();
  int hb = cnt_total[8 + e];
#pragma unroll
  for (int i = 0; i < 8; ++i) {
    int t = i * 256 + tid;
    int row = t >> 4, c = t & 15;
    if (row < nv) {
      short8 v = *(const short8*)&buf[row * 128 + ((c ^ ((row >> 2) & 3)) << 3)];
      *(short8*)&H[(size_t)(hb + (mi << 7) + row) * DHID + ni * 128 + (c << 3)] = v;
    }
  }
}

// ---------------- grouped GEMM2 + scale + scatter: out += w*(H @ W2^T + b2) ----------------
// 128x128 tile, K=512, BK=32 (16 steps), same tri-buffer depth-2 counted-vmcnt
// pipeline. A = H (contiguous). XCD-swizzled grid (4112 = 8*514).
__global__ __launch_bounds__(256, 3) void k_gemm2(
    const unsigned short* __restrict__ H, const unsigned short* __restrict__ w2b,
    const float* __restrict__ b2, const int* __restrict__ tok_list,
    const float* __restrict__ wt_list, const int* __restrict__ cnt_total,
    float* __restrict__ out) {
  __shared__ __align__(16) unsigned short buf[24576];
  __shared__ int s_tok[128];
  __shared__ float s_wt[128];

  int bid = (blockIdx.x & 7) * 514 + (blockIdx.x >> 3);
  int e = -1, loc = 0, cum = 0, cnte = 0;
#pragma unroll
  for (int ee = 0; ee < NEXP; ++ee) {
    int ct = cnt_total[ee];
    int nb = ((ct + 127) >> 7) * 2;
    if (e < 0 && bid < cum + nb) { e = ee; loc = bid - cum; cnte = ct; }
    cum += nb;
  }
  if (e < 0) return;
  int mi = loc >> 1, ni = loc & 1;
  int nv = cnte - (mi << 7); if (nv > 128) nv = 128;

  int tid = threadIdx.x;
  int lane = tid & 63, w = tid >> 6, l15 = lane & 15, lg = lane >> 4;
  int m0 = (w >> 1) * 64, n0 = (w & 1) * 64;

  float b2v[4];
#pragma unroll
  for (int nt = 0; nt < 4; ++nt) b2v[nt] = b2[e * DMODEL + ni * 128 + n0 + nt * 16 + l15];

  if (tid < 128) {
    int idx = e * T_TOK + (mi << 7) + (tid < nv ? tid : nv - 1);
    s_tok[tid] = tok_list[idx];
    s_wt[tid] = (tid < nv) ? wt_list[idx] : 0.f;
  }
  __syncthreads();

  int hb = cnt_total[8 + e];
  const unsigned short* hrows = H + (size_t)(hb + (mi << 7)) * DHID;
  const unsigned short* w2e = w2b + ((size_t)e * DMODEL + ni * 128) * DHID;

  auto stageA = [&](int cc) {
    int bb = (cc % 3) * 4096;
#pragma unroll
    for (int i = 0; i < 2; ++i) {
      int t = i * 256 + tid;
      int row = t >> 2, c = t & 3;
      gload16(hrows + (size_t)row * DHID + cc * 32 + ((c ^ ((row >> 1) & 3)) << 3),
              &buf[bb + (i * 256 + w * 64) * 8]);
    }
  };
  auto stageB = [&](int cc) {
    int bb = 12288 + (cc % 3) * 4096;
#pragma unroll
    for (int i = 0; i < 2; ++i) {
      int t = i * 256 + tid;
      int row = t >> 2, c = t & 3;
      gload16(w2e + (size_t)row * DHID + cc * 32 + ((c ^ ((row >> 1) & 3)) << 3),
              &buf[bb + (i * 256 + w * 64) * 8]);
    }
  };

  f32x4 acc[4][4];
#pragma unroll
  for (int mt = 0; mt < 4; ++mt)
#pragma unroll
    for (int nt = 0; nt < 4; ++nt) acc[mt][nt] = (f32x4){0.f, 0.f, 0.f, 0.f};

  stageB(0); stageA(0); stageB(1); stageA(1);
  asm volatile("s_waitcnt vmcnt(4)" ::: "memory");
  __builtin_amdgcn_s_barrier();
  __builtin_amdgcn_sched_barrier(0);

#pragma unroll
  for (int cc = 0; cc < 16; ++cc) {
    if (cc < 14) { stageB(cc + 2); stageA(cc + 2); }
    int ab = (cc % 3) * 4096, bb = 12288 + (cc % 3) * 4096;
    short8 a[4], b[4];
#pragma unroll
    for (int mt = 0; mt < 4; ++mt) {
      int r = m0 + mt * 16 + l15;
      a[mt] = *(const short8*)&buf[ab + r * 32 + ((lg ^ ((r >> 1) & 3)) << 3)];
    }
#pragma unroll
    for (int nt = 0; nt < 4; ++nt) {
      int r = n0 + nt * 16 + l15;
      b[nt] = *(const short8*)&buf[bb + r * 32 + ((lg ^ ((r >> 1) & 3)) << 3)];
    }
#pragma unroll
    for (int mt = 0; mt < 4; ++mt)
#pragma unroll
      for (int nt = 0; nt < 4; ++nt)
        acc[mt][nt] = __builtin_amdgcn_mfma_f32_16x16x32_bf16(a[mt], b[nt], acc[mt][nt], 0, 0, 0);
    if (cc < 14) { asm volatile("s_waitcnt vmcnt(4)" ::: "memory"); }
    else         { asm volatile("s_waitcnt vmcnt(0)" ::: "memory"); }
    __builtin_amdgcn_s_barrier();
    __builtin_amdgcn_sched_barrier(0);
  }

  // epilogue: out[tok, col] += wt * (acc + b2[col])
#pragma unroll
  for (int mt = 0; mt < 4; ++mt)
#pragma unroll
    for (int rr = 0; rr < 4; ++rr) {
      int row = m0 + mt * 16 + lg * 4 + rr;
      if (row < nv) {
        float wt = s_wt[row];
        float* orow = out + (size_t)s_tok[row] * DMODEL + ni * 128;
#pragma unroll
        for (int nt = 0; nt < 4; ++nt)
          atomicAdd(orow + n0 + nt * 16 + l15, wt * (acc[mt][rr >> 2 ? nt : nt][rr] + b2v[nt]));
      }
    }
}

extern "C" void kernel_launch(void* const* d_in, const int* in_sizes, int n_in,
                              void* d_out, int out_size, void* d_ws, size_t ws_size,
                              hipStream_t stream) {
  const float* x    = (const float*)d_in[0];
  const float* gate = (const float*)d_in[1];
  const float* w1   = (const float*)d_in[2];
  const float* b1   = (const float*)d_in[3];
  const float* w2   = (const float*)d_in[4];
  const float* b2   = (const float*)d_in[5];
  float* out = (float*)d_out;
  char* ws = (char*)d_ws;

  unsigned short* xb  = (unsigned short*)(ws);
  unsigned short* w1b = (unsigned short*)(ws + 67108864);
  unsigned short* w2b = (unsigned short*)(ws + 69206016);
  int*    tok_list  = (int*)(ws + 71303168);
  float*  wt_list   = (float*)(ws + 75497472);
  int*    pack      = (int*)(ws + 79691776);
  float2* tkw       = (float2*)(ws + 80216064);
  int*    part_cnt  = (int*)(ws + 81264640);
  float*  part_psum = (float*)(ws + 81526784);
  int*    block_off = (int*)(ws + 81788928);
  int*    cnt_total = (int*)(ws + 82051072);
  unsigned short* H = (unsigned short*)(ws + 83886080);

  hipMemsetAsync(d_out, 0, (size_t)out_size * 4, stream);
  k_wconv<<<1024, 256, 0, stream>>>(w1, w2, w1b, w2b);
  k_router<<<2048, 256, 0, stream>>>(x, gate, xb, pack, tkw, part_cnt, part_psum);
  k_scan<<<1, 512, 0, stream>>>(part_cnt, part_psum, block_off, cnt_total, out);
  k_scatter<<<2048, 64, 0, stream>>>(pack, tkw, block_off, tok_list, wt_list);
  k_gemm1<<<8224, 256, 0, stream>>>(xb, w1b, b1, tok_list, cnt_total, H);
  k_gemm2<<<4112, 256, 0, stream>>>(H, w2b, b2, tok_list, wt_list, cnt_total, out);
}